// Round 17
// baseline (426.544 us; speedup 1.0000x reference)
//
#include <hip/hip_runtime.h>
#include <math.h>

typedef float floatx2 __attribute__((ext_vector_type(2)));
typedef float floatx4 __attribute__((ext_vector_type(4)));
typedef short bf16x8 __attribute__((ext_vector_type(8)));
typedef _Float16 halfx2 __attribute__((ext_vector_type(2)));

#define NODE_MASK 0x07FFFFFF
#define LOG2E 1.4426950408889634f

__device__ __forceinline__ float wave_sum(float v){
#pragma unroll
  for (int m = 1; m < 64; m <<= 1) v += __shfl_xor(v, m, 64);
  return v;
}

__device__ __forceinline__ unsigned short bf16_of(float a){
  unsigned ua = __float_as_uint(a);
  ua = (ua + 0x7FFFu + ((ua >> 16) & 1u)) >> 16;
  return (unsigned short)ua;
}
__device__ __forceinline__ unsigned pack_bf16(float a, float b){
  unsigned ua = __float_as_uint(a), ub = __float_as_uint(b);
  ua = (ua + 0x7FFFu + ((ua >> 16) & 1u)) >> 16;
  ub = (ub + 0x7FFFu + ((ub >> 16) & 1u)) >> 16;
  return ua | (ub << 16);
}
__device__ __forceinline__ float2 unpack_bf16(unsigned p){
  float2 r;
  r.x = __uint_as_float(p << 16);
  r.y = __uint_as_float(p & 0xFFFF0000u);
  return r;
}
__device__ __forceinline__ bf16x8 to_bf16x8(float4 a, float4 b){
  bf16x8 r;
  r[0]=(short)bf16_of(a.x); r[1]=(short)bf16_of(a.y);
  r[2]=(short)bf16_of(a.z); r[3]=(short)bf16_of(a.w);
  r[4]=(short)bf16_of(b.x); r[5]=(short)bf16_of(b.y);
  r[6]=(short)bf16_of(b.z); r[7]=(short)bf16_of(b.w);
  return r;
}
__device__ __forceinline__ halfx2 f22h2(float a, float b){
  auto r = __builtin_amdgcn_cvt_pkrtz(a, b);
  return *(halfx2*)&r;
}
__device__ __forceinline__ float fdot2h(halfx2 a, halfx2 b, float c){
  return __builtin_amdgcn_fdot2(a, b, c, false);
}

// ---------------- CSR build (dst-major, self-loop first per node) ----------------
__global__ void k_deg_rank(const int* __restrict__ dst, int* __restrict__ deg,
                           int* __restrict__ rank, int e){
  int i = blockIdx.x*blockDim.x + threadIdx.x;
  if (i < e) rank[i] = atomicAdd(&deg[dst[i]], 1);
}

__global__ void k_scan_a(const int* __restrict__ deg, int* __restrict__ rowptr,
                         int* __restrict__ bsum, int n){
  __shared__ int sm[256];
  int i = blockIdx.x*256 + threadIdx.x;
  int v = (i < n) ? (deg[i] + 1) : 0;   // +1 self loop
  sm[threadIdx.x] = v; __syncthreads();
#pragma unroll
  for (int off = 1; off < 256; off <<= 1){
    int t = (threadIdx.x >= off) ? sm[threadIdx.x - off] : 0;
    __syncthreads();
    sm[threadIdx.x] += t;
    __syncthreads();
  }
  if (i < n) rowptr[i] = sm[threadIdx.x] - v;
  if (threadIdx.x == 255) bsum[blockIdx.x] = sm[255];
}

__global__ void k_scan_b(int* __restrict__ bsum, int* __restrict__ rowptr, int nb, int n){
  __shared__ int sm[256];
  int t = threadIdx.x;
  int v = (t < nb) ? bsum[t] : 0;
  sm[t] = v; __syncthreads();
#pragma unroll
  for (int off = 1; off < 256; off <<= 1){
    int x = (t >= off) ? sm[t - off] : 0;
    __syncthreads();
    sm[t] += x;
    __syncthreads();
  }
  if (t < nb) bsum[t] = sm[t] - v;
  if (t == 255) rowptr[n] = sm[255];
}

__global__ void k_scan_c_selfloop(int* __restrict__ rowptr, const int* __restrict__ bsum,
                                  int* __restrict__ csr,
                                  const int* __restrict__ batch,
                                  float* __restrict__ gc, int n){
  int i = blockIdx.x*256 + threadIdx.x;
  if (i < n){
    int r = rowptr[i] + bsum[blockIdx.x];
    rowptr[i] = r;
    csr[r] = i | (batch[i] << 27);
  }
  if (blockIdx.x == 0){
    gc[threadIdx.x] = 0.f;
    gc[threadIdx.x + 256] = 0.f;
  }
}

// atomic-free scatter: 4 edges/thread, independent chains
__global__ void k_scatter(const int* __restrict__ src, const int* __restrict__ dst,
                          const int* __restrict__ batch,
                          const int* __restrict__ rowptr, const int* __restrict__ rank,
                          int* __restrict__ csr, int* __restrict__ epos, int e){
  int i = (blockIdx.x*blockDim.x + threadIdx.x) * 4;
  if (i + 3 < e){
    int4 s4 = *(const int4*)&src[i];
    int4 d4 = *(const int4*)&dst[i];
    int4 r4 = *(const int4*)&rank[i];
    int p0 = rowptr[d4.x] + 1 + r4.x;
    int p1 = rowptr[d4.y] + 1 + r4.y;
    int p2 = rowptr[d4.z] + 1 + r4.z;
    int p3 = rowptr[d4.w] + 1 + r4.w;
    csr[p0] = s4.x | (batch[s4.x] << 27);
    csr[p1] = s4.y | (batch[s4.y] << 27);
    csr[p2] = s4.z | (batch[s4.z] << 27);
    csr[p3] = s4.w | (batch[s4.w] << 27);
    int4 ep; ep.x = p0 - d4.x - 1; ep.y = p1 - d4.y - 1;
    ep.z = p2 - d4.z - 1; ep.w = p3 - d4.w - 1;
    *(int4*)&epos[i] = ep;
  } else {
    for (int j = i; j < e; ++j){
      int d = dst[j], sv = src[j];
      int pos = rowptr[d] + 1 + rank[j];
      csr[pos] = sv | (batch[sv] << 27);
      epos[j] = pos - d - 1;
    }
  }
}

// ------- node transforms via MFMA: block = 64-node M-block; wave = one 16-col N-tile -------
template<int K>
__global__ __launch_bounds__(256)
void k_node_transform(const float* __restrict__ h,
                      const float* __restrict__ Wl, const float* __restrict__ bl,
                      const float* __restrict__ Wr, const float* __restrict__ br,
                      const float* __restrict__ Wres, const float* __restrict__ bias,
                      unsigned short* __restrict__ xl8, float* __restrict__ xr,
                      float* __restrict__ res, int n){
  const int KH = K / 32;
  int lane = threadIdx.x & 63;
  int nt   = threadIdx.x >> 6;      // wave = N-tile 0..3
  int nn = lane & 15, q = lane >> 4;
  int m0 = blockIdx.x * 64;
  if (m0 >= n) return;
  bf16x8 Af[4][KH];
#pragma unroll
  for (int t = 0; t < 4; ++t){
#pragma unroll
    for (int kh = 0; kh < KH; ++kh){
      int node = min(m0 + t*16 + nn, n - 1);
      const float* hp = h + (size_t)node*K + kh*32 + q*8;
      Af[t][kh] = to_bf16x8(*(const float4*)hp, *(const float4*)(hp + 4));
    }
  }
  int n0 = nt * 16;
  for (int sel = 0; sel < 3; ++sel){
    const float* Wp = (sel == 0) ? Wl : (sel == 1) ? Wr : Wres;
    const float* bp = (sel == 0) ? bl : (sel == 1) ? br : bias;
    bf16x8 Bf[KH];
#pragma unroll
    for (int kh = 0; kh < KH; ++kh){
#pragma unroll
      for (int j = 0; j < 8; ++j)
        Bf[kh][j] = (short)bf16_of(Wp[(kh*32 + q*8 + j)*64 + n0 + nn]);
    }
    float bv = bp[n0 + nn];
#pragma unroll
    for (int t = 0; t < 4; ++t){
      floatx4 acc = {bv, bv, bv, bv};
#pragma unroll
      for (int kh = 0; kh < KH; ++kh)
        acc = __builtin_amdgcn_mfma_f32_16x16x32_bf16(Af[t][kh], Bf[kh], acc, 0, 0, 0);
      int nodeb = m0 + t*16 + q*4;   // + reg = node ; col = n0+nn
      if (sel == 0){
#pragma unroll
        for (int reg = 0; reg < 4; ++reg){
          float v = acc[reg];
          float p = __shfl_xor(v, 1, 64);
          int node = nodeb + reg;
          if (!(nn & 1) && node < n)
            xl8[(size_t)node*32 + ((n0 + nn) >> 1)] =
              (unsigned short)__builtin_amdgcn_cvt_pk_fp8_f32(v, p, 0, false);
        }
      } else {
        float* op = (sel == 1) ? xr : res;
#pragma unroll
        for (int reg = 0; reg < 4; ++reg){
          int node = nodeb + reg;
          if (node < n) op[(size_t)node*64 + n0 + nn] = acc[reg];
        }
      }
    }
  }
}

// --- fused: edge softmax (no-max exp2, packed-f16 math, 4 slots, prefetch-2) + LN + relu ---
__global__ void k_gat_edge(const unsigned* __restrict__ xl_u, const float* __restrict__ xr,
                           const float* __restrict__ att,
                           const float* __restrict__ lng, const float* __restrict__ lnb,
                           const int* __restrict__ rowptr, const int* __restrict__ csr,
                           float* __restrict__ hio, int n){
  int node = (blockIdx.x*blockDim.x + threadIdx.x) >> 6;
  int lane = threadIdx.x & 63;
  if (node >= n) return;
  int sub = lane >> 4;
  int l   = lane & 15;
  size_t base = (size_t)node*64 + 4*l;
  float4 xrv  = *(const float4*)&xr[base];
  float4 attv = *(const float4*)&att[4*l];
  halfx2 xh0 = f22h2(xrv.x, xrv.y), xh1 = f22h2(xrv.z, xrv.w);
  halfx2 at0 = f22h2(attv.x*LOG2E, attv.y*LOG2E);
  halfx2 at1 = f22h2(attv.z*LOG2E, attv.w*LOG2E);
  halfx2 z2  = {(_Float16)0.f, (_Float16)0.f};
  halfx2 c02 = {(_Float16)0.2f, (_Float16)0.2f};
  int p0 = rowptr[node], p1 = rowptr[node+1];
  int deg = p1 - p0;
  int sreg = csr[p0 + min(lane, deg-1)];
  int rounds = (deg + 3) >> 2;
  float dsum = 0.f;
  float a0=0.f, a1=0.f, a2=0.f, a3=0.f;
  int e0 = sub;
  bool v0 = e0 < deg;
  int s0 = __shfl(sreg, v0 ? e0 : 0, 64) & NODE_MASK;
  unsigned x0 = xl_u[(size_t)s0*16 + l];
  int e1 = 4 + sub;
  bool v1 = e1 < deg;
  unsigned x1 = x0;
  if (rounds > 1){
    int s1;
    if (e1 < 64) s1 = __shfl(sreg, v1 ? e1 : 0, 64);
    else         s1 = csr[p0 + (v1 ? e1 : 0)];
    s1 &= NODE_MASK;
    x1 = xl_u[(size_t)s1*16 + l];
  }
  for (int r = 0; r < rounds; ++r){
    int en = 4*(r+2) + sub;
    bool vn = en < deg;
    unsigned xn = x0;
    if (r + 2 < rounds){
      int sn;
      if (en < 64) sn = __shfl(sreg, vn ? en : 0, 64);
      else         sn = csr[p0 + (vn ? en : 0)];
      sn &= NODE_MASK;
      xn = xl_u[(size_t)sn*16 + l];
    }
    floatx2 p01 = __builtin_amdgcn_cvt_pk_f32_fp8(x0, false);
    floatx2 p23 = __builtin_amdgcn_cvt_pk_f32_fp8(x0, true);
    halfx2 v0h = f22h2(p01.x, p01.y) + xh0;
    halfx2 v1h = f22h2(p23.x, p23.y) + xh1;
    halfx2 lr0 = __builtin_elementwise_min(v0h, z2) * c02 + __builtin_elementwise_max(v0h, z2);
    halfx2 lr1 = __builtin_elementwise_min(v1h, z2) * c02 + __builtin_elementwise_max(v1h, z2);
    float partial = fdot2h(lr1, at1, fdot2h(lr0, at0, 0.f));
#pragma unroll
    for (int mm = 1; mm < 16; mm <<= 1) partial += __shfl_xor(partial, mm, 64);
    float w = v0 ? exp2f(partial) : 0.f;
    dsum += w;
    a0 = fmaf(w, p01.x, a0);
    a1 = fmaf(w, p01.y, a1);
    a2 = fmaf(w, p23.x, a2);
    a3 = fmaf(w, p23.y, a3);
    x0 = x1; v0 = v1;
    x1 = xn; v1 = vn;
  }
#pragma unroll
  for (int off = 16; off < 64; off <<= 1){
    dsum += __shfl_xor(dsum, off, 64);
    a0 += __shfl_xor(a0, off, 64);
    a1 += __shfl_xor(a1, off, 64);
    a2 += __shfl_xor(a2, off, 64);
    a3 += __shfl_xor(a3, off, 64);
  }
  float4 resv = *(const float4*)&hio[base];
  float inv = __builtin_amdgcn_rcpf(dsum);
  float ox = fmaf(a0, inv, resv.x);
  float oy = fmaf(a1, inv, resv.y);
  float oz = fmaf(a2, inv, resv.z);
  float ow = fmaf(a3, inv, resv.w);
  float mean = wave_sum(ox + oy + oz + ow) * (1.f/256.f);
  float dx = ox - mean, dy = oy - mean, dz = oz - mean, dw = ow - mean;
  float var = wave_sum(fmaf(dx,dx, fmaf(dy,dy, fmaf(dz,dz, dw*dw)))) * (1.f/256.f);
  float rstd = rsqrtf(var + 1e-5f);
  if (sub == 0){
    float4 lg = *(const float4*)&lng[4*l];
    float4 lb = *(const float4*)&lnb[4*l];
    float4 out;
    out.x = fmaxf(fmaf(dx*rstd, lg.x, lb.x), 0.f);
    out.y = fmaxf(fmaf(dy*rstd, lg.y, lb.y), 0.f);
    out.z = fmaxf(fmaf(dz*rstd, lg.z, lb.z), 0.f);
    out.w = fmaxf(fmaf(dw*rstd, lg.w, lb.w), 0.f);
    *(float4*)&hio[base] = out;
  }
}

// ---------------- global add pool (batch is sorted) ----------------
__global__ void k_pool(const float* __restrict__ h, const int* __restrict__ batch,
                       float* __restrict__ gc, int n){
  int wid  = (blockIdx.x*blockDim.x + threadIdx.x) >> 6;
  int lane = threadIdx.x & 63;
  int n0 = wid*64;
  if (n0 >= n) return;
  int n1 = min(n0+64, n);
  int curg = batch[n0];
  float s = 0.f;
  for (int i = n0; i < n1; ++i){
    int g = batch[i];
    if (g != curg){ atomicAdd(&gc[curg*64+lane], s); s = 0.f; curg = g; }
    s += h[(size_t)i*64 + lane];
  }
  atomicAdd(&gc[curg*64+lane], s);
}

// ------- G[g] = gc[g] @ W1c + b1, emitted as packed half2 table (8 x 64 dwords) -------
__global__ void k_graph_proj(const float* __restrict__ gc, const float* __restrict__ W1,
                             const float* __restrict__ b1, unsigned* __restrict__ Gh){
  int g = threadIdx.x >> 7;
  int j = threadIdx.x & 127;
  float a = b1[j];
#pragma unroll 8
  for (int k = 0; k < 64; ++k) a = fmaf(gc[g*64+k], W1[(128+k)*128 + j], a);
  float p = __shfl_xor(a, 1, 64);
  if (!(j & 1)){
    halfx2 hv = f22h2(a, p);
    Gh[g*64 + (j >> 1)] = *(unsigned*)&hv;
  }
}

// ---- node proj via MFMA: block = 64 nodes; wave = 4 of 16 (half,nt) tile-columns ----
__global__ __launch_bounds__(256)
void k_node_proj(const float* __restrict__ nr, const float* __restrict__ W1,
                 unsigned short* __restrict__ Au16, unsigned* __restrict__ Bu, int n){
  int lane = threadIdx.x & 63;
  int wave = threadIdx.x >> 6;      // 0..3
  int nn = lane & 15, q = lane >> 4;
  int m0 = blockIdx.x * 64;
  if (m0 >= n) return;
  bf16x8 Af[4][2];
#pragma unroll
  for (int t = 0; t < 4; ++t){
#pragma unroll
    for (int kh = 0; kh < 2; ++kh){
      int node = min(m0 + t*16 + nn, n - 1);
      const float* hp = nr + (size_t)node*64 + kh*32 + q*8;
      Af[t][kh] = to_bf16x8(*(const float4*)hp, *(const float4*)(hp + 4));
    }
  }
  for (int half = 0; half < 2; ++half){     // 0: W1a -> Au ; 1: W1b -> Bu
#pragma unroll
    for (int ni = 0; ni < 2; ++ni){
      int nt = wave + ni*4;
      int n0 = nt * 16;
      bf16x8 Bf[2];
#pragma unroll
      for (int kh = 0; kh < 2; ++kh){
#pragma unroll
        for (int j = 0; j < 8; ++j)
          Bf[kh][j] = (short)bf16_of(W1[(half*64 + kh*32 + q*8 + j)*128 + n0 + nn]);
      }
#pragma unroll
      for (int t = 0; t < 4; ++t){
        floatx4 acc = {0.f, 0.f, 0.f, 0.f};
#pragma unroll
        for (int kh = 0; kh < 2; ++kh)
          acc = __builtin_amdgcn_mfma_f32_16x16x32_bf16(Af[t][kh], Bf[kh], acc, 0, 0, 0);
        int nodeb = m0 + t*16 + q*4;
#pragma unroll
        for (int reg = 0; reg < 4; ++reg){
          float v = acc[reg];
          float p = __shfl_xor(v, 1, 64);
          int node = nodeb + reg;
          if (!(nn & 1) && node < n){
            int j = (n0 + nn) >> 1;
            if (half == 0)
              Au16[(size_t)node*64 + j] =
                (unsigned short)__builtin_amdgcn_cvt_pk_fp8_f32(v, p, 0, false);
            else
              Bu[(size_t)node*64 + j] = pack_bf16(v, p);
          }
        }
      }
    }
  }
}

// -- final per-edge MLP, dst-major, packed-f16: B[d]/W2 pre-packed, G from half2 table --
__global__ void k_edge_out_csr(const uint2* __restrict__ Au2, const uint4* __restrict__ Bu4,
                               const unsigned* __restrict__ Gh,
                               const int* __restrict__ rowptr, const int* __restrict__ csr,
                               const float* __restrict__ W2, const float* __restrict__ b2,
                               float* __restrict__ tmp, int n){
  int node = (blockIdx.x*blockDim.x + threadIdx.x) >> 6;
  int lane = threadIdx.x & 63;
  if (node >= n) return;
  int sub = lane >> 4;
  int l   = lane & 15;
  int p0 = rowptr[node];
  int deg2 = rowptr[node+1] - p0 - 1;
  if (deg2 <= 0) return;
  int sreg = csr[p0 + 1 + min(lane, deg2-1)];
  uint4 b = Bu4[(size_t)node*16 + l];
  float2 b01 = unpack_bf16(b.x), b23 = unpack_bf16(b.y);
  float2 b45 = unpack_bf16(b.z), b67 = unpack_bf16(b.w);
  halfx2 bh0 = f22h2(b01.x, b01.y), bh1 = f22h2(b23.x, b23.y);
  halfx2 bh2 = f22h2(b45.x, b45.y), bh3 = f22h2(b67.x, b67.y);
  float4 w0 = *(const float4*)&W2[8*l];
  float4 w1 = *(const float4*)&W2[8*l + 4];
  halfx2 wh0 = f22h2(w0.x, w0.y), wh1 = f22h2(w0.z, w0.w);
  halfx2 wh2 = f22h2(w1.x, w1.y), wh3 = f22h2(w1.z, w1.w);
  halfx2 z2 = {(_Float16)0.f, (_Float16)0.f};
  float b2v = b2[0];
  int rbase = p0 - node;
  int rounds = (deg2 + 3) >> 2;
  int e0 = sub;
  bool v0 = e0 < deg2;
  int c0 = __shfl(sreg, v0 ? e0 : 0, 64);
  uint2 A0 = Au2[(size_t)(c0 & NODE_MASK)*16 + l];
  int e1 = 4 + sub;
  bool v1 = e1 < deg2;
  int c1 = c0; uint2 A1 = A0;
  if (rounds > 1){
    if (e1 < 64) c1 = __shfl(sreg, v1 ? e1 : 0, 64);
    else         c1 = csr[p0 + 1 + (v1 ? e1 : 0)];
    A1 = Au2[(size_t)(c1 & NODE_MASK)*16 + l];
  }
  for (int r = 0; r < rounds; ++r){
    int en = 4*(r+2) + sub;
    bool vn = en < deg2;
    int cn = c0; uint2 An = A0;
    if (r + 2 < rounds){
      if (en < 64) cn = __shfl(sreg, vn ? en : 0, 64);
      else         cn = csr[p0 + 1 + (vn ? en : 0)];
      An = Au2[(size_t)(cn & NODE_MASK)*16 + l];
    }
    int g = ((unsigned)c0) >> 27;
    uint4 gv = *(const uint4*)(Gh + g*64 + 4*l);
    halfx2 gh0 = *(halfx2*)&gv.x, gh1 = *(halfx2*)&gv.y;
    halfx2 gh2 = *(halfx2*)&gv.z, gh3 = *(halfx2*)&gv.w;
    floatx2 a01 = __builtin_amdgcn_cvt_pk_f32_fp8(A0.x, false);
    floatx2 a23 = __builtin_amdgcn_cvt_pk_f32_fp8(A0.x, true);
    floatx2 a45 = __builtin_amdgcn_cvt_pk_f32_fp8(A0.y, false);
    floatx2 a67 = __builtin_amdgcn_cvt_pk_f32_fp8(A0.y, true);
    halfx2 h0 = __builtin_elementwise_max(f22h2(a01.x, a01.y) + bh0 + gh0, z2);
    halfx2 h1 = __builtin_elementwise_max(f22h2(a23.x, a23.y) + bh1 + gh1, z2);
    halfx2 h2 = __builtin_elementwise_max(f22h2(a45.x, a45.y) + bh2 + gh2, z2);
    halfx2 h3 = __builtin_elementwise_max(f22h2(a67.x, a67.y) + bh3 + gh3, z2);
    float part = fdot2h(h3, wh3, fdot2h(h2, wh2, fdot2h(h1, wh1, fdot2h(h0, wh0, 0.f))));
#pragma unroll
    for (int mm = 1; mm < 16; mm <<= 1) part += __shfl_xor(part, mm, 64);
    if (l == 0 && v0) tmp[rbase + 4*r + sub] = part + b2v;
    c0 = c1; A0 = A1; v0 = v1;
    c1 = cn; A1 = An; v1 = vn;
  }
}

// ---- out[i] = tmp[epos[i]] ----
__global__ void k_remap(const float* __restrict__ tmp, const int* __restrict__ epos,
                        float* __restrict__ out, int e){
  int i = blockIdx.x*blockDim.x + threadIdx.x;
  if (i < e) out[i] = tmp[epos[i]];
}

extern "C" void kernel_launch(void* const* d_in, const int* in_sizes, int n_in,
                              void* d_out, int out_size, void* d_ws, size_t ws_size,
                              hipStream_t stream){
  const float* x     = (const float*)d_in[0];
  const int*   ei    = (const int*)d_in[1];
  const int*   batch = (const int*)d_in[2];
  const int N = in_sizes[2];
  const int E = in_sizes[1] / 2;
  const int* src = ei;
  const int* dst = ei + E;

  unsigned* W = (unsigned*)d_ws;
  const size_t N16 = (size_t)N * 16;
  const size_t N32 = (size_t)N * 32;
  const size_t N64 = (size_t)N * 64;
  unsigned short* xl8 = (unsigned short*)W;          // N x 64 fp8
  float* xr = (float*)(W + N16);
  float* hE = (float*)(W + N16 + N64);
  float* hD = (float*)(W + N16 + 2*N64);
  unsigned short* Au16 = (unsigned short*)W;         // N x 64 ushorts (fp8 pairs)
  unsigned* Bu = W + N32;                            // N x 64 dwords bf16
  int* rowptr = (int*)(W + N16 + 3*N64);             // N+2
  int* deg    = rowptr + (N + 2);                    // N
  int* csr    = deg + N;                             // N + E
  int* epos   = csr + (N + E);                       // E
  int* rank   = epos + E;                            // E
  float* gc   = (float*)(rank + E);                  // 8*64
  unsigned* Gh = (unsigned*)(gc + 512);              // 8*64 packed half2
  int* bsum   = (int*)(Gh + 512);                    // ceil(N/256)
  float* tmp  = (float*)(bsum + 256);                // E floats

  const int NB = (N + 255) / 256;
  const int NT64 = (N + 63) / 64;

  // ---- CSR build ----
  (void)hipMemsetAsync(deg, 0, (size_t)N*4, stream);
  k_deg_rank <<<(E+255)/256, 256, 0, stream>>>(dst, deg, rank, E);
  k_scan_a   <<<NB, 256, 0, stream>>>(deg, rowptr, bsum, N);
  k_scan_b   <<<1, 256, 0, stream>>>(bsum, rowptr, NB, N);
  k_scan_c_selfloop<<<NB, 256, 0, stream>>>(rowptr, bsum, csr, batch, gc, N);
  k_scatter  <<<(E/4+255)/256, 256, 0, stream>>>(src, dst, batch, rowptr, rank, csr, epos, E);

  // ---- 3 GATv2 layers ----
  const float* h = x;
  float* hn = hD;
  for (int l = 0; l < 3; ++l){
    const float* Wl   = (const float*)d_in[3 + 9*l + 0];
    const float* bl   = (const float*)d_in[3 + 9*l + 1];
    const float* Wr   = (const float*)d_in[3 + 9*l + 2];
    const float* br   = (const float*)d_in[3 + 9*l + 3];
    const float* att  = (const float*)d_in[3 + 9*l + 4];
    const float* Wres = (const float*)d_in[3 + 9*l + 5];
    const float* bias = (const float*)d_in[3 + 9*l + 6];
    const float* lng  = (const float*)d_in[3 + 9*l + 7];
    const float* lnb  = (const float*)d_in[3 + 9*l + 8];
    if (l == 0)
      k_node_transform<32><<<NT64, 256, 0, stream>>>(h, Wl, bl, Wr, br, Wres, bias, xl8, xr, hn, N);
    else
      k_node_transform<64><<<NT64, 256, 0, stream>>>(h, Wl, bl, Wr, br, Wres, bias, xl8, xr, hn, N);
    k_gat_edge<<<(N+3)/4, 256, 0, stream>>>((const unsigned*)xl8, xr, att, lng, lnb, rowptr, csr, hn, N);
    h = hn;
    hn = (l == 0) ? hE : hD;   // final node_repr = hD
  }

  // ---- readout ----
  const float* W1 = (const float*)d_in[30];
  const float* b1 = (const float*)d_in[31];
  const float* W2 = (const float*)d_in[32];
  const float* b2 = (const float*)d_in[33];

  int pool_waves = (N + 63) / 64;
  k_pool      <<<(pool_waves+3)/4, 256, 0, stream>>>(hD, batch, gc, N);
  k_graph_proj<<<1, 1024, 0, stream>>>(gc, W1, b1, Gh);
  k_node_proj <<<NT64, 256, 0, stream>>>(hD, W1, Au16, Bu, N);
  k_edge_out_csr<<<(N+3)/4, 256, 0, stream>>>((const uint2*)Au16, (const uint4*)Bu, Gh,
                                              rowptr, csr, W2, b2, tmp, N);
  k_remap     <<<(E+255)/256, 256, 0, stream>>>(tmp, epos, (float*)d_out, E);
}

// Round 18
// 422.166 us; speedup vs baseline: 1.0104x; 1.0104x over previous
//
#include <hip/hip_runtime.h>
#include <math.h>

typedef float floatx2 __attribute__((ext_vector_type(2)));
typedef float floatx4 __attribute__((ext_vector_type(4)));
typedef short bf16x8 __attribute__((ext_vector_type(8)));
typedef _Float16 halfx2 __attribute__((ext_vector_type(2)));

#define NODE_MASK 0x07FFFFFF
#define LOG2E 1.4426950408889634f

__device__ __forceinline__ float wave_sum(float v){
#pragma unroll
  for (int m = 1; m < 64; m <<= 1) v += __shfl_xor(v, m, 64);
  return v;
}

__device__ __forceinline__ unsigned short bf16_of(float a){
  unsigned ua = __float_as_uint(a);
  ua = (ua + 0x7FFFu + ((ua >> 16) & 1u)) >> 16;
  return (unsigned short)ua;
}
__device__ __forceinline__ unsigned pack_bf16(float a, float b){
  unsigned ua = __float_as_uint(a), ub = __float_as_uint(b);
  ua = (ua + 0x7FFFu + ((ua >> 16) & 1u)) >> 16;
  ub = (ub + 0x7FFFu + ((ub >> 16) & 1u)) >> 16;
  return ua | (ub << 16);
}
__device__ __forceinline__ float2 unpack_bf16(unsigned p){
  float2 r;
  r.x = __uint_as_float(p << 16);
  r.y = __uint_as_float(p & 0xFFFF0000u);
  return r;
}
__device__ __forceinline__ bf16x8 to_bf16x8(float4 a, float4 b){
  bf16x8 r;
  r[0]=(short)bf16_of(a.x); r[1]=(short)bf16_of(a.y);
  r[2]=(short)bf16_of(a.z); r[3]=(short)bf16_of(a.w);
  r[4]=(short)bf16_of(b.x); r[5]=(short)bf16_of(b.y);
  r[6]=(short)bf16_of(b.z); r[7]=(short)bf16_of(b.w);
  return r;
}
__device__ __forceinline__ halfx2 f22h2(float a, float b){
  auto r = __builtin_amdgcn_cvt_pkrtz(a, b);
  return *(halfx2*)&r;
}
__device__ __forceinline__ float fdot2h(halfx2 a, halfx2 b, float c){
  return __builtin_amdgcn_fdot2(a, b, c, false);
}

// ---------------- CSR build (dst-major, self-loop first per node) ----------------
// 4 edges/thread: independent atomic chains + coalesced int4 rank store
__global__ void k_deg_rank(const int* __restrict__ dst, int* __restrict__ deg,
                           int* __restrict__ rank, int e){
  int i = (blockIdx.x*blockDim.x + threadIdx.x) * 4;
  if (i + 3 < e){
    int4 d4 = *(const int4*)&dst[i];
    int4 r4;
    r4.x = atomicAdd(&deg[d4.x], 1);
    r4.y = atomicAdd(&deg[d4.y], 1);
    r4.z = atomicAdd(&deg[d4.z], 1);
    r4.w = atomicAdd(&deg[d4.w], 1);
    *(int4*)&rank[i] = r4;
  } else {
    for (int j = i; j < e; ++j) rank[j] = atomicAdd(&deg[dst[j]], 1);
  }
}

__global__ void k_scan_a(const int* __restrict__ deg, int* __restrict__ rowptr,
                         int* __restrict__ bsum, int n){
  __shared__ int sm[256];
  int i = blockIdx.x*256 + threadIdx.x;
  int v = (i < n) ? (deg[i] + 1) : 0;   // +1 self loop
  sm[threadIdx.x] = v; __syncthreads();
#pragma unroll
  for (int off = 1; off < 256; off <<= 1){
    int t = (threadIdx.x >= off) ? sm[threadIdx.x - off] : 0;
    __syncthreads();
    sm[threadIdx.x] += t;
    __syncthreads();
  }
  if (i < n) rowptr[i] = sm[threadIdx.x] - v;
  if (threadIdx.x == 255) bsum[blockIdx.x] = sm[255];
}

__global__ void k_scan_b(int* __restrict__ bsum, int* __restrict__ rowptr, int nb, int n){
  __shared__ int sm[256];
  int t = threadIdx.x;
  int v = (t < nb) ? bsum[t] : 0;
  sm[t] = v; __syncthreads();
#pragma unroll
  for (int off = 1; off < 256; off <<= 1){
    int x = (t >= off) ? sm[t - off] : 0;
    __syncthreads();
    sm[t] += x;
    __syncthreads();
  }
  if (t < nb) bsum[t] = sm[t] - v;
  if (t == 255) rowptr[n] = sm[255];
}

__global__ void k_scan_c_selfloop(int* __restrict__ rowptr, const int* __restrict__ bsum,
                                  int* __restrict__ csr,
                                  const int* __restrict__ batch,
                                  float* __restrict__ gc, int n){
  int i = blockIdx.x*256 + threadIdx.x;
  if (i < n){
    int r = rowptr[i] + bsum[blockIdx.x];
    rowptr[i] = r;
    csr[r] = i | (batch[i] << 27);
  }
  if (blockIdx.x == 0){
    gc[threadIdx.x] = 0.f;
    gc[threadIdx.x + 256] = 0.f;
  }
}

// atomic-free scatter: 4 edges/thread, independent chains
__global__ void k_scatter(const int* __restrict__ src, const int* __restrict__ dst,
                          const int* __restrict__ batch,
                          const int* __restrict__ rowptr, const int* __restrict__ rank,
                          int* __restrict__ csr, int* __restrict__ epos, int e){
  int i = (blockIdx.x*blockDim.x + threadIdx.x) * 4;
  if (i + 3 < e){
    int4 s4 = *(const int4*)&src[i];
    int4 d4 = *(const int4*)&dst[i];
    int4 r4 = *(const int4*)&rank[i];
    int p0 = rowptr[d4.x] + 1 + r4.x;
    int p1 = rowptr[d4.y] + 1 + r4.y;
    int p2 = rowptr[d4.z] + 1 + r4.z;
    int p3 = rowptr[d4.w] + 1 + r4.w;
    csr[p0] = s4.x | (batch[s4.x] << 27);
    csr[p1] = s4.y | (batch[s4.y] << 27);
    csr[p2] = s4.z | (batch[s4.z] << 27);
    csr[p3] = s4.w | (batch[s4.w] << 27);
    int4 ep; ep.x = p0 - d4.x - 1; ep.y = p1 - d4.y - 1;
    ep.z = p2 - d4.z - 1; ep.w = p3 - d4.w - 1;
    *(int4*)&epos[i] = ep;
  } else {
    for (int j = i; j < e; ++j){
      int d = dst[j], sv = src[j];
      int pos = rowptr[d] + 1 + rank[j];
      csr[pos] = sv | (batch[sv] << 27);
      epos[j] = pos - d - 1;
    }
  }
}

// ------- node transforms via MFMA: block = 64-node M-block; wave = one 16-col N-tile -------
template<int K>
__global__ __launch_bounds__(256)
void k_node_transform(const float* __restrict__ h,
                      const float* __restrict__ Wl, const float* __restrict__ bl,
                      const float* __restrict__ Wr, const float* __restrict__ br,
                      const float* __restrict__ Wres, const float* __restrict__ bias,
                      unsigned short* __restrict__ xl8, float* __restrict__ xr,
                      float* __restrict__ res, int n){
  const int KH = K / 32;
  int lane = threadIdx.x & 63;
  int nt   = threadIdx.x >> 6;      // wave = N-tile 0..3
  int nn = lane & 15, q = lane >> 4;
  int m0 = blockIdx.x * 64;
  if (m0 >= n) return;
  bf16x8 Af[4][KH];
#pragma unroll
  for (int t = 0; t < 4; ++t){
#pragma unroll
    for (int kh = 0; kh < KH; ++kh){
      int node = min(m0 + t*16 + nn, n - 1);
      const float* hp = h + (size_t)node*K + kh*32 + q*8;
      Af[t][kh] = to_bf16x8(*(const float4*)hp, *(const float4*)(hp + 4));
    }
  }
  int n0 = nt * 16;
  for (int sel = 0; sel < 3; ++sel){
    const float* Wp = (sel == 0) ? Wl : (sel == 1) ? Wr : Wres;
    const float* bp = (sel == 0) ? bl : (sel == 1) ? br : bias;
    bf16x8 Bf[KH];
#pragma unroll
    for (int kh = 0; kh < KH; ++kh){
#pragma unroll
      for (int j = 0; j < 8; ++j)
        Bf[kh][j] = (short)bf16_of(Wp[(kh*32 + q*8 + j)*64 + n0 + nn]);
    }
    float bv = bp[n0 + nn];
#pragma unroll
    for (int t = 0; t < 4; ++t){
      floatx4 acc = {bv, bv, bv, bv};
#pragma unroll
      for (int kh = 0; kh < KH; ++kh)
        acc = __builtin_amdgcn_mfma_f32_16x16x32_bf16(Af[t][kh], Bf[kh], acc, 0, 0, 0);
      int nodeb = m0 + t*16 + q*4;   // + reg = node ; col = n0+nn
      if (sel == 0){
#pragma unroll
        for (int reg = 0; reg < 4; ++reg){
          float v = acc[reg];
          float p = __shfl_xor(v, 1, 64);
          int node = nodeb + reg;
          if (!(nn & 1) && node < n)
            xl8[(size_t)node*32 + ((n0 + nn) >> 1)] =
              (unsigned short)__builtin_amdgcn_cvt_pk_fp8_f32(v, p, 0, false);
        }
      } else {
        float* op = (sel == 1) ? xr : res;
#pragma unroll
        for (int reg = 0; reg < 4; ++reg){
          int node = nodeb + reg;
          if (node < n) op[(size_t)node*64 + n0 + nn] = acc[reg];
        }
      }
    }
  }
}

// --- fused: edge softmax (no-max exp2, packed-f16 math, 4 slots, prefetch-2) + LN + relu ---
__global__ void k_gat_edge(const unsigned* __restrict__ xl_u, const float* __restrict__ xr,
                           const float* __restrict__ att,
                           const float* __restrict__ lng, const float* __restrict__ lnb,
                           const int* __restrict__ rowptr, const int* __restrict__ csr,
                           float* __restrict__ hio, int n){
  int node = (blockIdx.x*blockDim.x + threadIdx.x) >> 6;
  int lane = threadIdx.x & 63;
  if (node >= n) return;
  int sub = lane >> 4;
  int l   = lane & 15;
  size_t base = (size_t)node*64 + 4*l;
  float4 xrv  = *(const float4*)&xr[base];
  float4 attv = *(const float4*)&att[4*l];
  halfx2 xh0 = f22h2(xrv.x, xrv.y), xh1 = f22h2(xrv.z, xrv.w);
  halfx2 at0 = f22h2(attv.x*LOG2E, attv.y*LOG2E);
  halfx2 at1 = f22h2(attv.z*LOG2E, attv.w*LOG2E);
  halfx2 z2  = {(_Float16)0.f, (_Float16)0.f};
  halfx2 c02 = {(_Float16)0.2f, (_Float16)0.2f};
  int p0 = rowptr[node], p1 = rowptr[node+1];
  int deg = p1 - p0;
  int sreg = csr[p0 + min(lane, deg-1)];
  int rounds = (deg + 3) >> 2;
  float dsum = 0.f;
  float a0=0.f, a1=0.f, a2=0.f, a3=0.f;
  int e0 = sub;
  bool v0 = e0 < deg;
  int s0 = __shfl(sreg, v0 ? e0 : 0, 64) & NODE_MASK;
  unsigned x0 = xl_u[(size_t)s0*16 + l];
  int e1 = 4 + sub;
  bool v1 = e1 < deg;
  unsigned x1 = x0;
  if (rounds > 1){
    int s1;
    if (e1 < 64) s1 = __shfl(sreg, v1 ? e1 : 0, 64);
    else         s1 = csr[p0 + (v1 ? e1 : 0)];
    s1 &= NODE_MASK;
    x1 = xl_u[(size_t)s1*16 + l];
  }
  for (int r = 0; r < rounds; ++r){
    int en = 4*(r+2) + sub;
    bool vn = en < deg;
    unsigned xn = x0;
    if (r + 2 < rounds){
      int sn;
      if (en < 64) sn = __shfl(sreg, vn ? en : 0, 64);
      else         sn = csr[p0 + (vn ? en : 0)];
      sn &= NODE_MASK;
      xn = xl_u[(size_t)sn*16 + l];
    }
    floatx2 p01 = __builtin_amdgcn_cvt_pk_f32_fp8(x0, false);
    floatx2 p23 = __builtin_amdgcn_cvt_pk_f32_fp8(x0, true);
    halfx2 v0h = f22h2(p01.x, p01.y) + xh0;
    halfx2 v1h = f22h2(p23.x, p23.y) + xh1;
    halfx2 lr0 = __builtin_elementwise_min(v0h, z2) * c02 + __builtin_elementwise_max(v0h, z2);
    halfx2 lr1 = __builtin_elementwise_min(v1h, z2) * c02 + __builtin_elementwise_max(v1h, z2);
    float partial = fdot2h(lr1, at1, fdot2h(lr0, at0, 0.f));
#pragma unroll
    for (int mm = 1; mm < 16; mm <<= 1) partial += __shfl_xor(partial, mm, 64);
    float w = v0 ? exp2f(partial) : 0.f;
    dsum += w;
    a0 = fmaf(w, p01.x, a0);
    a1 = fmaf(w, p01.y, a1);
    a2 = fmaf(w, p23.x, a2);
    a3 = fmaf(w, p23.y, a3);
    x0 = x1; v0 = v1;
    x1 = xn; v1 = vn;
  }
#pragma unroll
  for (int off = 16; off < 64; off <<= 1){
    dsum += __shfl_xor(dsum, off, 64);
    a0 += __shfl_xor(a0, off, 64);
    a1 += __shfl_xor(a1, off, 64);
    a2 += __shfl_xor(a2, off, 64);
    a3 += __shfl_xor(a3, off, 64);
  }
  float4 resv = *(const float4*)&hio[base];
  float inv = __builtin_amdgcn_rcpf(dsum);
  float ox = fmaf(a0, inv, resv.x);
  float oy = fmaf(a1, inv, resv.y);
  float oz = fmaf(a2, inv, resv.z);
  float ow = fmaf(a3, inv, resv.w);
  float mean = wave_sum(ox + oy + oz + ow) * (1.f/256.f);
  float dx = ox - mean, dy = oy - mean, dz = oz - mean, dw = ow - mean;
  float var = wave_sum(fmaf(dx,dx, fmaf(dy,dy, fmaf(dz,dz, dw*dw)))) * (1.f/256.f);
  float rstd = rsqrtf(var + 1e-5f);
  if (sub == 0){
    float4 lg = *(const float4*)&lng[4*l];
    float4 lb = *(const float4*)&lnb[4*l];
    float4 out;
    out.x = fmaxf(fmaf(dx*rstd, lg.x, lb.x), 0.f);
    out.y = fmaxf(fmaf(dy*rstd, lg.y, lb.y), 0.f);
    out.z = fmaxf(fmaf(dz*rstd, lg.z, lb.z), 0.f);
    out.w = fmaxf(fmaf(dw*rstd, lg.w, lb.w), 0.f);
    *(float4*)&hio[base] = out;
  }
}

// ---------------- global add pool (batch is sorted) ----------------
__global__ void k_pool(const float* __restrict__ h, const int* __restrict__ batch,
                       float* __restrict__ gc, int n){
  int wid  = (blockIdx.x*blockDim.x + threadIdx.x) >> 6;
  int lane = threadIdx.x & 63;
  int n0 = wid*64;
  if (n0 >= n) return;
  int n1 = min(n0+64, n);
  int curg = batch[n0];
  float s = 0.f;
  for (int i = n0; i < n1; ++i){
    int g = batch[i];
    if (g != curg){ atomicAdd(&gc[curg*64+lane], s); s = 0.f; curg = g; }
    s += h[(size_t)i*64 + lane];
  }
  atomicAdd(&gc[curg*64+lane], s);
}

// ------- G[g] = gc[g] @ W1c + b1, emitted as packed half2 table (8 x 64 dwords) -------
__global__ void k_graph_proj(const float* __restrict__ gc, const float* __restrict__ W1,
                             const float* __restrict__ b1, unsigned* __restrict__ Gh){
  int g = threadIdx.x >> 7;
  int j = threadIdx.x & 127;
  float a = b1[j];
#pragma unroll 8
  for (int k = 0; k < 64; ++k) a = fmaf(gc[g*64+k], W1[(128+k)*128 + j], a);
  float p = __shfl_xor(a, 1, 64);
  if (!(j & 1)){
    halfx2 hv = f22h2(a, p);
    Gh[g*64 + (j >> 1)] = *(unsigned*)&hv;
  }
}

// ---- node proj via MFMA: block = 64 nodes; wave = 4 of 16 (half,nt) tile-columns ----
__global__ __launch_bounds__(256)
void k_node_proj(const float* __restrict__ nr, const float* __restrict__ W1,
                 unsigned short* __restrict__ Au16, unsigned* __restrict__ Bu, int n){
  int lane = threadIdx.x & 63;
  int wave = threadIdx.x >> 6;      // 0..3
  int nn = lane & 15, q = lane >> 4;
  int m0 = blockIdx.x * 64;
  if (m0 >= n) return;
  bf16x8 Af[4][2];
#pragma unroll
  for (int t = 0; t < 4; ++t){
#pragma unroll
    for (int kh = 0; kh < 2; ++kh){
      int node = min(m0 + t*16 + nn, n - 1);
      const float* hp = nr + (size_t)node*64 + kh*32 + q*8;
      Af[t][kh] = to_bf16x8(*(const float4*)hp, *(const float4*)(hp + 4));
    }
  }
  for (int half = 0; half < 2; ++half){     // 0: W1a -> Au ; 1: W1b -> Bu
#pragma unroll
    for (int ni = 0; ni < 2; ++ni){
      int nt = wave + ni*4;
      int n0 = nt * 16;
      bf16x8 Bf[2];
#pragma unroll
      for (int kh = 0; kh < 2; ++kh){
#pragma unroll
        for (int j = 0; j < 8; ++j)
          Bf[kh][j] = (short)bf16_of(W1[(half*64 + kh*32 + q*8 + j)*128 + n0 + nn]);
      }
#pragma unroll
      for (int t = 0; t < 4; ++t){
        floatx4 acc = {0.f, 0.f, 0.f, 0.f};
#pragma unroll
        for (int kh = 0; kh < 2; ++kh)
          acc = __builtin_amdgcn_mfma_f32_16x16x32_bf16(Af[t][kh], Bf[kh], acc, 0, 0, 0);
        int nodeb = m0 + t*16 + q*4;
#pragma unroll
        for (int reg = 0; reg < 4; ++reg){
          float v = acc[reg];
          float p = __shfl_xor(v, 1, 64);
          int node = nodeb + reg;
          if (!(nn & 1) && node < n){
            int j = (n0 + nn) >> 1;
            if (half == 0)
              Au16[(size_t)node*64 + j] =
                (unsigned short)__builtin_amdgcn_cvt_pk_fp8_f32(v, p, 0, false);
            else
              Bu[(size_t)node*64 + j] = pack_bf16(v, p);
          }
        }
      }
    }
  }
}

// -- final per-edge MLP, dst-major, packed-f16: B[d]/W2 pre-packed, G from half2 table --
__global__ void k_edge_out_csr(const uint2* __restrict__ Au2, const uint4* __restrict__ Bu4,
                               const unsigned* __restrict__ Gh,
                               const int* __restrict__ rowptr, const int* __restrict__ csr,
                               const float* __restrict__ W2, const float* __restrict__ b2,
                               float* __restrict__ tmp, int n){
  int node = (blockIdx.x*blockDim.x + threadIdx.x) >> 6;
  int lane = threadIdx.x & 63;
  if (node >= n) return;
  int sub = lane >> 4;
  int l   = lane & 15;
  int p0 = rowptr[node];
  int deg2 = rowptr[node+1] - p0 - 1;
  if (deg2 <= 0) return;
  int sreg = csr[p0 + 1 + min(lane, deg2-1)];
  uint4 b = Bu4[(size_t)node*16 + l];
  float2 b01 = unpack_bf16(b.x), b23 = unpack_bf16(b.y);
  float2 b45 = unpack_bf16(b.z), b67 = unpack_bf16(b.w);
  halfx2 bh0 = f22h2(b01.x, b01.y), bh1 = f22h2(b23.x, b23.y);
  halfx2 bh2 = f22h2(b45.x, b45.y), bh3 = f22h2(b67.x, b67.y);
  float4 w0 = *(const float4*)&W2[8*l];
  float4 w1 = *(const float4*)&W2[8*l + 4];
  halfx2 wh0 = f22h2(w0.x, w0.y), wh1 = f22h2(w0.z, w0.w);
  halfx2 wh2 = f22h2(w1.x, w1.y), wh3 = f22h2(w1.z, w1.w);
  halfx2 z2 = {(_Float16)0.f, (_Float16)0.f};
  float b2v = b2[0];
  int rbase = p0 - node;
  int rounds = (deg2 + 3) >> 2;
  int e0 = sub;
  bool v0 = e0 < deg2;
  int c0 = __shfl(sreg, v0 ? e0 : 0, 64);
  uint2 A0 = Au2[(size_t)(c0 & NODE_MASK)*16 + l];
  int e1 = 4 + sub;
  bool v1 = e1 < deg2;
  int c1 = c0; uint2 A1 = A0;
  if (rounds > 1){
    if (e1 < 64) c1 = __shfl(sreg, v1 ? e1 : 0, 64);
    else         c1 = csr[p0 + 1 + (v1 ? e1 : 0)];
    A1 = Au2[(size_t)(c1 & NODE_MASK)*16 + l];
  }
  for (int r = 0; r < rounds; ++r){
    int en = 4*(r+2) + sub;
    bool vn = en < deg2;
    int cn = c0; uint2 An = A0;
    if (r + 2 < rounds){
      if (en < 64) cn = __shfl(sreg, vn ? en : 0, 64);
      else         cn = csr[p0 + 1 + (vn ? en : 0)];
      An = Au2[(size_t)(cn & NODE_MASK)*16 + l];
    }
    int g = ((unsigned)c0) >> 27;
    uint4 gv = *(const uint4*)(Gh + g*64 + 4*l);
    halfx2 gh0 = *(halfx2*)&gv.x, gh1 = *(halfx2*)&gv.y;
    halfx2 gh2 = *(halfx2*)&gv.z, gh3 = *(halfx2*)&gv.w;
    floatx2 a01 = __builtin_amdgcn_cvt_pk_f32_fp8(A0.x, false);
    floatx2 a23 = __builtin_amdgcn_cvt_pk_f32_fp8(A0.x, true);
    floatx2 a45 = __builtin_amdgcn_cvt_pk_f32_fp8(A0.y, false);
    floatx2 a67 = __builtin_amdgcn_cvt_pk_f32_fp8(A0.y, true);
    halfx2 h0 = __builtin_elementwise_max(f22h2(a01.x, a01.y) + bh0 + gh0, z2);
    halfx2 h1 = __builtin_elementwise_max(f22h2(a23.x, a23.y) + bh1 + gh1, z2);
    halfx2 h2 = __builtin_elementwise_max(f22h2(a45.x, a45.y) + bh2 + gh2, z2);
    halfx2 h3 = __builtin_elementwise_max(f22h2(a67.x, a67.y) + bh3 + gh3, z2);
    float part = fdot2h(h3, wh3, fdot2h(h2, wh2, fdot2h(h1, wh1, fdot2h(h0, wh0, 0.f))));
#pragma unroll
    for (int mm = 1; mm < 16; mm <<= 1) part += __shfl_xor(part, mm, 64);
    if (l == 0 && v0) tmp[rbase + 4*r + sub] = part + b2v;
    c0 = c1; A0 = A1; v0 = v1;
    c1 = cn; A1 = An; v1 = vn;
  }
}

// ---- out[i] = tmp[epos[i]] ----
__global__ void k_remap(const float* __restrict__ tmp, const int* __restrict__ epos,
                        float* __restrict__ out, int e){
  int i = blockIdx.x*blockDim.x + threadIdx.x;
  if (i < e) out[i] = tmp[epos[i]];
}

extern "C" void kernel_launch(void* const* d_in, const int* in_sizes, int n_in,
                              void* d_out, int out_size, void* d_ws, size_t ws_size,
                              hipStream_t stream){
  const float* x     = (const float*)d_in[0];
  const int*   ei    = (const int*)d_in[1];
  const int*   batch = (const int*)d_in[2];
  const int N = in_sizes[2];
  const int E = in_sizes[1] / 2;
  const int* src = ei;
  const int* dst = ei + E;

  unsigned* W = (unsigned*)d_ws;
  const size_t N16 = (size_t)N * 16;
  const size_t N32 = (size_t)N * 32;
  const size_t N64 = (size_t)N * 64;
  unsigned short* xl8 = (unsigned short*)W;          // N x 64 fp8
  float* xr = (float*)(W + N16);
  float* hE = (float*)(W + N16 + N64);
  float* hD = (float*)(W + N16 + 2*N64);
  unsigned short* Au16 = (unsigned short*)W;         // N x 64 ushorts (fp8 pairs)
  unsigned* Bu = W + N32;                            // N x 64 dwords bf16
  int* rowptr = (int*)(W + N16 + 3*N64);             // N+2
  int* deg    = rowptr + (N + 2);                    // N
  int* csr    = deg + N;                             // N + E
  int* epos   = csr + (N + E);                       // E
  int* rank   = epos + E;                            // E
  float* gc   = (float*)(rank + E);                  // 8*64
  unsigned* Gh = (unsigned*)(gc + 512);              // 8*64 packed half2
  int* bsum   = (int*)(Gh + 512);                    // ceil(N/256)
  float* tmp  = (float*)(bsum + 256);                // E floats

  const int NB = (N + 255) / 256;
  const int NT64 = (N + 63) / 64;

  // ---- CSR build ----
  (void)hipMemsetAsync(deg, 0, (size_t)N*4, stream);
  k_deg_rank <<<(E/4+255)/256, 256, 0, stream>>>(dst, deg, rank, E);
  k_scan_a   <<<NB, 256, 0, stream>>>(deg, rowptr, bsum, N);
  k_scan_b   <<<1, 256, 0, stream>>>(bsum, rowptr, NB, N);
  k_scan_c_selfloop<<<NB, 256, 0, stream>>>(rowptr, bsum, csr, batch, gc, N);
  k_scatter  <<<(E/4+255)/256, 256, 0, stream>>>(src, dst, batch, rowptr, rank, csr, epos, E);

  // ---- 3 GATv2 layers ----
  const float* h = x;
  float* hn = hD;
  for (int l = 0; l < 3; ++l){
    const float* Wl   = (const float*)d_in[3 + 9*l + 0];
    const float* bl   = (const float*)d_in[3 + 9*l + 1];
    const float* Wr   = (const float*)d_in[3 + 9*l + 2];
    const float* br   = (const float*)d_in[3 + 9*l + 3];
    const float* att  = (const float*)d_in[3 + 9*l + 4];
    const float* Wres = (const float*)d_in[3 + 9*l + 5];
    const float* bias = (const float*)d_in[3 + 9*l + 6];
    const float* lng  = (const float*)d_in[3 + 9*l + 7];
    const float* lnb  = (const float*)d_in[3 + 9*l + 8];
    if (l == 0)
      k_node_transform<32><<<NT64, 256, 0, stream>>>(h, Wl, bl, Wr, br, Wres, bias, xl8, xr, hn, N);
    else
      k_node_transform<64><<<NT64, 256, 0, stream>>>(h, Wl, bl, Wr, br, Wres, bias, xl8, xr, hn, N);
    k_gat_edge<<<(N+3)/4, 256, 0, stream>>>((const unsigned*)xl8, xr, att, lng, lnb, rowptr, csr, hn, N);
    h = hn;
    hn = (l == 0) ? hE : hD;   // final node_repr = hD
  }

  // ---- readout ----
  const float* W1 = (const float*)d_in[30];
  const float* b1 = (const float*)d_in[31];
  const float* W2 = (const float*)d_in[32];
  const float* b2 = (const float*)d_in[33];

  int pool_waves = (N + 63) / 64;
  k_pool      <<<(pool_waves+3)/4, 256, 0, stream>>>(hD, batch, gc, N);
  k_graph_proj<<<1, 1024, 0, stream>>>(gc, W1, b1, Gh);
  k_node_proj <<<NT64, 256, 0, stream>>>(hD, W1, Au16, Bu, N);
  k_edge_out_csr<<<(N+3)/4, 256, 0, stream>>>((const uint2*)Au16, (const uint4*)Bu, Gh,
                                              rowptr, csr, W2, b2, tmp, N);
  k_remap     <<<(E+255)/256, 256, 0, stream>>>(tmp, epos, (float*)d_out, E);
}